// Round 15
// baseline (92.439 us; speedup 1.0000x reference)
//
#include <hip/hip_runtime.h>
#include <cstddef>

#define B_SZ 32768
#define H_SZ 1024
#define N_SZ 4
#define C_SZ 1000
#define ROW_BLOCKS 512
#define ROWS_PER_BLOCK 64    // B_SZ / ROW_BLOCKS

// ---- workspace layout (in floats) ----
#define PART_SUM   0                                  // 512*1024
#define PART_SQ    (PART_SUM + ROW_BLOCKS*H_SZ)       // 512*1024
#define WSUM_PART  (PART_SQ  + ROW_BLOCKS*H_SZ)       // 512
#define A_OFF      (WSUM_PART + ROW_BLOCKS)           // 1024  (gamma * inv_std)
#define C_OFF      (A_OFF + H_SZ)                     // 1024  (beta - mean * a)
#define SCAL_OFF   (C_OFF + H_SZ)                     // 1 (inv_wsum)  (+7 pad)
#define PCN_OFF    (SCAL_OFF + 8)                     // 4000 (p_cn, zeroed in k_colsum)

// ---- output layout (floats) ----
#define OUT_IG  ((size_t)B_SZ * H_SZ)                 // 33554432
#define OUT_R   (OUT_IG + 1)                          // 33554433

// Pass 1: weighted column sums, SKIPPING masked-out rows (~half the read
// traffic; branch is block-uniform). 512 blocks x 64 rows.
__global__ void __launch_bounds__(256) k_colsum(const float* __restrict__ h,
                                                const int* __restrict__ mask,
                                                float* __restrict__ ws) {
    const int rb   = blockIdx.x;
    const int t    = threadIdx.x;          // 0..255
    const int row0 = rb * ROWS_PER_BLOCK;
    const int col  = t * 4;

    // zero p_cn: blocks 0..499 each clear 8 floats (500*8 = 4000, disjoint)
    if (rb < 500 && t < 8) ws[PCN_OFF + rb * 8 + t] = 0.f;

    float4 sA = make_float4(0.f, 0.f, 0.f, 0.f);
    float4 qA = make_float4(0.f, 0.f, 0.f, 0.f);
    float4 sB = make_float4(0.f, 0.f, 0.f, 0.f);
    float4 qB = make_float4(0.f, 0.f, 0.f, 0.f);
    int mc = 0;

    const float* p = h + (size_t)row0 * H_SZ + col;
    for (int r = 0; r < ROWS_PER_BLOCK; r += 2) {
        const int ma = mask[row0 + r];
        const int mb = mask[row0 + r + 1];
        mc += ma + mb;
        if (ma) {                         // block-uniform branch
            const float4 xa = *(const float4*)(p);
            sA.x += xa.x; sA.y += xa.y; sA.z += xa.z; sA.w += xa.w;
            qA.x = fmaf(xa.x, xa.x, qA.x); qA.y = fmaf(xa.y, xa.y, qA.y);
            qA.z = fmaf(xa.z, xa.z, qA.z); qA.w = fmaf(xa.w, xa.w, qA.w);
        }
        if (mb) {
            const float4 xb = *(const float4*)(p + H_SZ);
            sB.x += xb.x; sB.y += xb.y; sB.z += xb.z; sB.w += xb.w;
            qB.x = fmaf(xb.x, xb.x, qB.x); qB.y = fmaf(xb.y, xb.y, qB.y);
            qB.z = fmaf(xb.z, xb.z, qB.z); qB.w = fmaf(xb.w, xb.w, qB.w);
        }
        p += 2 * H_SZ;
    }
    sA.x += sB.x; sA.y += sB.y; sA.z += sB.z; sA.w += sB.w;
    qA.x += qB.x; qA.y += qB.y; qA.z += qB.z; qA.w += qB.w;

    *(float4*)(ws + PART_SUM + (size_t)rb * H_SZ + col) = sA;
    *(float4*)(ws + PART_SQ  + (size_t)rb * H_SZ + col) = qA;
    if (t == 0) ws[WSUM_PART + rb] = (float)mc;
}

// Pass 2: finalize mean/var -> a[h], c[h], inv_wsum.
// 128 blocks; block handles 8 columns, 32 strips of 16 partials each.
__global__ void __launch_bounds__(256) k_colfinal(const float* __restrict__ gamma,
                                                  const float* __restrict__ beta,
                                                  float* __restrict__ ws) {
    __shared__ float red[256];
    __shared__ float sh_s[32][9];
    __shared__ float sh_q[32][9];
    const int t = threadIdx.x;

    // wsum: every block reduces the 512 mask-count partials
    float w = 0.f;
#pragma unroll
    for (int i = 0; i < ROW_BLOCKS / 256; ++i) w += ws[WSUM_PART + i * 256 + t];
    red[t] = w;
    __syncthreads();
    for (int sft = 128; sft > 0; sft >>= 1) {
        if (t < sft) red[t] += red[t + sft];
        __syncthreads();
    }
    const float wsum = red[0];

    const int c8    = t & 7;
    const int strip = t >> 3;                  // 0..31
    const int col   = blockIdx.x * 8 + c8;

    float s = 0.f, q = 0.f;
    const int rb0 = strip * (ROW_BLOCKS / 32);
    for (int k = 0; k < ROW_BLOCKS / 32; ++k) {
        s += ws[PART_SUM + (size_t)(rb0 + k) * H_SZ + col];
        q += ws[PART_SQ  + (size_t)(rb0 + k) * H_SZ + col];
    }
    sh_s[strip][c8] = s;
    sh_q[strip][c8] = q;
    __syncthreads();

    if (t < 8) {
        float S = 0.f, Q = 0.f;
#pragma unroll
        for (int k = 0; k < 32; ++k) { S += sh_s[k][t]; Q += sh_q[k][t]; }
        const int hcol = blockIdx.x * 8 + t;
        const float inv_w = 1.0f / wsum;
        const float mean  = S * inv_w;
        float var = Q * inv_w - mean * mean;
        if (var < 0.f) var = 0.f;
        const float istd = rsqrtf(var + 1e-5f);
        const float a = gamma[hcol] * istd;
        const float c = beta[hcol] - mean * a;
        ws[A_OFF + hcol] = a;
        ws[C_OFF + hcol] = c;
        if (blockIdx.x == 0 && t == 0) ws[SCAL_OFF] = inv_w;
    }
}

// Pass 3: fused normalize + (BxH)@(Hx4) + softmax + argmax routing + p_cn atomics.
// 4 rows/wave (W amortization, R11 lesson) but (256,4): 16 waves/CU for more
// latency hiding. NAMED accumulators (no runtime-indexed array).
__global__ void __launch_bounds__(256, 4) k_fused(const float* __restrict__ hin,
                                                  const int* __restrict__ mask,
                                                  const int* __restrict__ labels,
                                                  const float* __restrict__ W,
                                                  const float* __restrict__ bias,
                                                  const float* __restrict__ ws,
                                                  float* __restrict__ out,
                                                  float* __restrict__ pcn) {
    const int wid  = threadIdx.x >> 6;
    const int lane = threadIdx.x & 63;
    const int gw   = blockIdx.x * 4 + wid;    // 0..8191
    const int row0 = gw * 4;

    // preload this lane's 16 W rows (cols h = ch*256 + lane*4 + j), and a/c
    float4 Wr[4][4];
    float4 a4[4], c4[4];
#pragma unroll
    for (int ch = 0; ch < 4; ++ch) {
        const int h = ch * 256 + lane * 4;
        a4[ch] = *(const float4*)(ws + A_OFF + h);
        c4[ch] = *(const float4*)(ws + C_OFF + h);
#pragma unroll
        for (int j = 0; j < 4; ++j)
            Wr[ch][j] = *(const float4*)(W + (size_t)(h + j) * 4);
    }
    const float inv_w = ws[SCAL_OFF];

    float4 accA, accB, accC, accD;

#define ROW_BODY(ACC, RIDX)                                                     \
    {                                                                           \
        const int row = row0 + (RIDX);                                          \
        const float* xr   = hin + (size_t)row * H_SZ;                           \
        float*       outr = out + (size_t)row * H_SZ;                           \
        ACC = make_float4(0.f, 0.f, 0.f, 0.f);                                  \
        _Pragma("unroll")                                                       \
        for (int ch = 0; ch < 4; ++ch) {                                        \
            const int h = ch * 256 + lane * 4;                                  \
            const float4 x = *(const float4*)(xr + h);                          \
            float4 hn;                                                          \
            hn.x = fmaf(x.x, a4[ch].x, c4[ch].x);                               \
            hn.y = fmaf(x.y, a4[ch].y, c4[ch].y);                               \
            hn.z = fmaf(x.z, a4[ch].z, c4[ch].z);                               \
            hn.w = fmaf(x.w, a4[ch].w, c4[ch].w);                               \
            *(float4*)(outr + h) = hn;                                          \
            ACC.x = fmaf(hn.x, Wr[ch][0].x, ACC.x);                             \
            ACC.y = fmaf(hn.x, Wr[ch][0].y, ACC.y);                             \
            ACC.z = fmaf(hn.x, Wr[ch][0].z, ACC.z);                             \
            ACC.w = fmaf(hn.x, Wr[ch][0].w, ACC.w);                             \
            ACC.x = fmaf(hn.y, Wr[ch][1].x, ACC.x);                             \
            ACC.y = fmaf(hn.y, Wr[ch][1].y, ACC.y);                             \
            ACC.z = fmaf(hn.y, Wr[ch][1].z, ACC.z);                             \
            ACC.w = fmaf(hn.y, Wr[ch][1].w, ACC.w);                             \
            ACC.x = fmaf(hn.z, Wr[ch][2].x, ACC.x);                             \
            ACC.y = fmaf(hn.z, Wr[ch][2].y, ACC.y);                             \
            ACC.z = fmaf(hn.z, Wr[ch][2].z, ACC.z);                             \
            ACC.w = fmaf(hn.z, Wr[ch][2].w, ACC.w);                             \
            ACC.x = fmaf(hn.w, Wr[ch][3].x, ACC.x);                             \
            ACC.y = fmaf(hn.w, Wr[ch][3].y, ACC.y);                             \
            ACC.z = fmaf(hn.w, Wr[ch][3].z, ACC.z);                             \
            ACC.w = fmaf(hn.w, Wr[ch][3].w, ACC.w);                             \
        }                                                                       \
    }

    ROW_BODY(accA, 0)
    ROW_BODY(accB, 1)
    ROW_BODY(accC, 2)
    ROW_BODY(accD, 3)
#undef ROW_BODY

    // batched wave reduce-all: 4 independent chains (one per row)
#pragma unroll
    for (int off = 1; off < 64; off <<= 1) {
        accA.x += __shfl_xor(accA.x, off); accA.y += __shfl_xor(accA.y, off);
        accA.z += __shfl_xor(accA.z, off); accA.w += __shfl_xor(accA.w, off);
        accB.x += __shfl_xor(accB.x, off); accB.y += __shfl_xor(accB.y, off);
        accB.z += __shfl_xor(accB.z, off); accB.w += __shfl_xor(accB.w, off);
        accC.x += __shfl_xor(accC.x, off); accC.y += __shfl_xor(accC.y, off);
        accC.z += __shfl_xor(accC.z, off); accC.w += __shfl_xor(accC.w, off);
        accD.x += __shfl_xor(accD.x, off); accD.y += __shfl_xor(accD.y, off);
        accD.z += __shfl_xor(accD.z, off); accD.w += __shfl_xor(accD.w, off);
    }

    // lane-parallel epilogue: lane<16 handles (row r = lane>>2, expert n = lane&3)
    if (lane < 16) {
        const int r   = lane >> 2;
        const int n   = lane & 3;
        const int row = row0 + r;

        const float4 av = (r == 0) ? accA : (r == 1) ? accB : (r == 2) ? accC : accD;

        const float s0 = av.x + bias[0];
        const float s1 = av.y + bias[1];
        const float s2 = av.z + bias[2];
        const float s3 = av.w + bias[3];

        // first-occurrence argmax (matches jnp.argmax)
        int amax = 0; float best = s0;
        if (s1 > best) { best = s1; amax = 1; }
        if (s2 > best) { best = s2; amax = 2; }
        if (s3 > best) { best = s3; amax = 3; }

        const float e0 = expf(s0 - best);
        const float e1 = expf(s1 - best);
        const float e2 = expf(s2 - best);
        const float e3 = expf(s3 - best);
        const float inv = 1.0f / (e0 + e1 + e2 + e3);

        const int m = mask[row];
        const float rv = (m && n == amax) ? 1.0f : 0.0f;
        out[OUT_R + (size_t)row * 4 + n] = rv;
        if (m) {
            const float en = (n == 0 ? e0 : n == 1 ? e1 : n == 2 ? e2 : e3);
            atomicAdd(&pcn[labels[row] * 4 + n], en * inv * inv_w);
        }
    }
}

// Pass 4: info-gain finalize over p_cn (1000 x 4) -> scalar
__global__ void __launch_bounds__(256) k_ig(const float* __restrict__ pcn,
                                            float* __restrict__ out) {
    __shared__ float red[256];
    __shared__ float pn_sh[4];
    const int t = threadIdx.x;

    float pn[4] = {0.f, 0.f, 0.f, 0.f};
    for (int c = t; c < C_SZ; c += 256) {
        pn[0] += pcn[c * 4 + 0];
        pn[1] += pcn[c * 4 + 1];
        pn[2] += pcn[c * 4 + 2];
        pn[3] += pcn[c * 4 + 3];
    }
#pragma unroll
    for (int n = 0; n < 4; ++n) {
        red[t] = pn[n];
        __syncthreads();
        for (int sft = 128; sft > 0; sft >>= 1) {
            if (t < sft) red[t] += red[t + sft];
            __syncthreads();
        }
        if (t == 0) pn_sh[n] = red[0];
        __syncthreads();
    }

    const float l0 = 2.0f * logf(pn_sh[0] + 1e-30f);
    const float l1 = 2.0f * logf(pn_sh[1] + 1e-30f);
    const float l2 = 2.0f * logf(pn_sh[2] + 1e-30f);
    const float l3 = 2.0f * logf(pn_sh[3] + 1e-30f);

    float kv = 0.f;
    for (int c = t; c < C_SZ; c += 256) {
        const float v0 = pcn[c * 4 + 0];
        const float v1 = pcn[c * 4 + 1];
        const float v2 = pcn[c * 4 + 2];
        const float v3 = pcn[c * 4 + 3];
        const float pc  = v0 + v1 + v2 + v3;
        const float lpc = logf(pc + 1e-30f);
        kv += v0 * (logf(v0 + 1e-30f) - lpc - l0);
        kv += v1 * (logf(v1 + 1e-30f) - lpc - l1);
        kv += v2 * (logf(v2 + 1e-30f) - lpc - l2);
        kv += v3 * (logf(v3 + 1e-30f) - lpc - l3);
    }
    red[t] = kv;
    __syncthreads();
    for (int sft = 128; sft > 0; sft >>= 1) {
        if (t < sft) red[t] += red[t + sft];
        __syncthreads();
    }
    if (t == 0) out[OUT_IG] = -red[0];
}

extern "C" void kernel_launch(void* const* d_in, const int* in_sizes, int n_in,
                              void* d_out, int out_size, void* d_ws, size_t ws_size,
                              hipStream_t stream) {
    const int*   ig_mask = (const int*)d_in[0];
    const float* h_net   = (const float*)d_in[1];
    const int*   labels  = (const int*)d_in[2];
    const float* gamma   = (const float*)d_in[3];
    const float* beta    = (const float*)d_in[4];
    const float* W       = (const float*)d_in[5];
    const float* b       = (const float*)d_in[6];

    float* out = (float*)d_out;
    float* ws  = (float*)d_ws;

    k_colsum<<<ROW_BLOCKS, 256, 0, stream>>>(h_net, ig_mask, ws);
    k_colfinal<<<H_SZ / 8, 256, 0, stream>>>(gamma, beta, ws);
    k_fused<<<B_SZ / 16, 256, 0, stream>>>(h_net, ig_mask, labels, W, b, ws, out,
                                           ws + PCN_OFF);
    k_ig<<<1, 256, 0, stream>>>(ws + PCN_OFF, out);
}

// Round 16
// 82.513 us; speedup vs baseline: 1.1203x; 1.1203x over previous
//
#include <hip/hip_runtime.h>
#include <cstddef>

#define B_SZ 32768
#define H_SZ 1024
#define N_SZ 4
#define C_SZ 1000
#define ROW_BLOCKS 1024
#define ROWS_PER_BLOCK 32    // B_SZ / ROW_BLOCKS

// ---- workspace layout (in floats) ----
#define PART_SUM   0                                  // 1024*1024
#define PART_SQ    (PART_SUM + ROW_BLOCKS*H_SZ)       // 1024*1024
#define WSUM_PART  (PART_SQ  + ROW_BLOCKS*H_SZ)       // 1024
#define A_OFF      (WSUM_PART + ROW_BLOCKS)           // 1024  (gamma * inv_std)
#define C_OFF      (A_OFF + H_SZ)                     // 1024  (beta - mean * a)
#define SCAL_OFF   (C_OFF + H_SZ)                     // 1 (inv_wsum)  (+7 pad)
#define PCN_OFF    (SCAL_OFF + 8)                     // 4000 (p_cn, zeroed in k_colsum)

// ---- output layout (floats) ----
#define OUT_IG  ((size_t)B_SZ * H_SZ)                 // 33554432
#define OUT_R   (OUT_IG + 1)                          // 33554433

// Pass 1: weighted column sums, SKIPPING masked-out rows (~half the read
// traffic; branch is block-uniform). 1024 blocks x 32 rows, 4 blocks/CU.
__global__ void __launch_bounds__(256) k_colsum(const float* __restrict__ h,
                                                const int* __restrict__ mask,
                                                float* __restrict__ ws) {
    const int rb   = blockIdx.x;
    const int t    = threadIdx.x;          // 0..255
    const int row0 = rb * ROWS_PER_BLOCK;
    const int col  = t * 4;

    // zero p_cn: blocks 0..499 each clear 8 floats (500*8 = 4000, disjoint)
    if (rb < 500 && t < 8) ws[PCN_OFF + rb * 8 + t] = 0.f;

    float4 sA = make_float4(0.f, 0.f, 0.f, 0.f);
    float4 qA = make_float4(0.f, 0.f, 0.f, 0.f);
    float4 sB = make_float4(0.f, 0.f, 0.f, 0.f);
    float4 qB = make_float4(0.f, 0.f, 0.f, 0.f);
    int mc = 0;

    const float* p = h + (size_t)row0 * H_SZ + col;
#pragma unroll
    for (int r = 0; r < ROWS_PER_BLOCK; r += 2) {
        const int ma = mask[row0 + r];
        const int mb = mask[row0 + r + 1];
        mc += ma + mb;
        if (ma) {                         // block-uniform branch
            const float4 xa = *(const float4*)(p);
            sA.x += xa.x; sA.y += xa.y; sA.z += xa.z; sA.w += xa.w;
            qA.x = fmaf(xa.x, xa.x, qA.x); qA.y = fmaf(xa.y, xa.y, qA.y);
            qA.z = fmaf(xa.z, xa.z, qA.z); qA.w = fmaf(xa.w, xa.w, qA.w);
        }
        if (mb) {
            const float4 xb = *(const float4*)(p + H_SZ);
            sB.x += xb.x; sB.y += xb.y; sB.z += xb.z; sB.w += xb.w;
            qB.x = fmaf(xb.x, xb.x, qB.x); qB.y = fmaf(xb.y, xb.y, qB.y);
            qB.z = fmaf(xb.z, xb.z, qB.z); qB.w = fmaf(xb.w, xb.w, qB.w);
        }
        p += 2 * H_SZ;
    }
    sA.x += sB.x; sA.y += sB.y; sA.z += sB.z; sA.w += sB.w;
    qA.x += qB.x; qA.y += qB.y; qA.z += qB.z; qA.w += qB.w;

    *(float4*)(ws + PART_SUM + (size_t)rb * H_SZ + col) = sA;
    *(float4*)(ws + PART_SQ  + (size_t)rb * H_SZ + col) = qA;
    if (t == 0) ws[WSUM_PART + rb] = (float)mc;
}

// Pass 2: finalize mean/var -> a[h], c[h], inv_wsum.
// 128 blocks; block handles 8 columns, 32 strips of 32 partials each.
__global__ void __launch_bounds__(256) k_colfinal(const float* __restrict__ gamma,
                                                  const float* __restrict__ beta,
                                                  float* __restrict__ ws) {
    __shared__ float red[256];
    __shared__ float sh_s[32][9];
    __shared__ float sh_q[32][9];
    const int t = threadIdx.x;

    // wsum: every block reduces the 1024 mask-count partials
    float w = 0.f;
#pragma unroll
    for (int i = 0; i < ROW_BLOCKS / 256; ++i) w += ws[WSUM_PART + i * 256 + t];
    red[t] = w;
    __syncthreads();
    for (int sft = 128; sft > 0; sft >>= 1) {
        if (t < sft) red[t] += red[t + sft];
        __syncthreads();
    }
    const float wsum = red[0];

    const int c8    = t & 7;
    const int strip = t >> 3;                  // 0..31
    const int col   = blockIdx.x * 8 + c8;

    float s = 0.f, q = 0.f;
    const int rb0 = strip * (ROW_BLOCKS / 32);
    for (int k = 0; k < ROW_BLOCKS / 32; ++k) {
        s += ws[PART_SUM + (size_t)(rb0 + k) * H_SZ + col];
        q += ws[PART_SQ  + (size_t)(rb0 + k) * H_SZ + col];
    }
    sh_s[strip][c8] = s;
    sh_q[strip][c8] = q;
    __syncthreads();

    if (t < 8) {
        float S = 0.f, Q = 0.f;
#pragma unroll
        for (int k = 0; k < 32; ++k) { S += sh_s[k][t]; Q += sh_q[k][t]; }
        const int hcol = blockIdx.x * 8 + t;
        const float inv_w = 1.0f / wsum;
        const float mean  = S * inv_w;
        float var = Q * inv_w - mean * mean;
        if (var < 0.f) var = 0.f;
        const float istd = rsqrtf(var + 1e-5f);
        const float a = gamma[hcol] * istd;
        const float c = beta[hcol] - mean * a;
        ws[A_OFF + hcol] = a;
        ws[C_OFF + hcol] = c;
        if (blockIdx.x == 0 && t == 0) ws[SCAL_OFF] = inv_w;
    }
}

// Pass 3: fused normalize + (BxH)@(Hx4) + softmax + argmax routing + p_cn atomics.
// R12 best config: each wave owns 4 rows, (256,3). W preloaded in registers;
// NAMED accumulators (no runtime-indexed array -> no LDS demotion).
__global__ void __launch_bounds__(256, 3) k_fused(const float* __restrict__ hin,
                                                  const int* __restrict__ mask,
                                                  const int* __restrict__ labels,
                                                  const float* __restrict__ W,
                                                  const float* __restrict__ bias,
                                                  const float* __restrict__ ws,
                                                  float* __restrict__ out,
                                                  float* __restrict__ pcn) {
    const int wid  = threadIdx.x >> 6;
    const int lane = threadIdx.x & 63;
    const int gw   = blockIdx.x * 4 + wid;    // 0..8191
    const int row0 = gw * 4;

    // preload this lane's 16 W rows (cols h = ch*256 + lane*4 + j), and a/c
    float4 Wr[4][4];
    float4 a4[4], c4[4];
#pragma unroll
    for (int ch = 0; ch < 4; ++ch) {
        const int h = ch * 256 + lane * 4;
        a4[ch] = *(const float4*)(ws + A_OFF + h);
        c4[ch] = *(const float4*)(ws + C_OFF + h);
#pragma unroll
        for (int j = 0; j < 4; ++j)
            Wr[ch][j] = *(const float4*)(W + (size_t)(h + j) * 4);
    }
    const float inv_w = ws[SCAL_OFF];

    float4 accA, accB, accC, accD;

#define ROW_BODY(ACC, RIDX)                                                     \
    {                                                                           \
        const int row = row0 + (RIDX);                                          \
        const float* xr   = hin + (size_t)row * H_SZ;                           \
        float*       outr = out + (size_t)row * H_SZ;                           \
        ACC = make_float4(0.f, 0.f, 0.f, 0.f);                                  \
        _Pragma("unroll")                                                       \
        for (int ch = 0; ch < 4; ++ch) {                                        \
            const int h = ch * 256 + lane * 4;                                  \
            const float4 x = *(const float4*)(xr + h);                          \
            float4 hn;                                                          \
            hn.x = fmaf(x.x, a4[ch].x, c4[ch].x);                               \
            hn.y = fmaf(x.y, a4[ch].y, c4[ch].y);                               \
            hn.z = fmaf(x.z, a4[ch].z, c4[ch].z);                               \
            hn.w = fmaf(x.w, a4[ch].w, c4[ch].w);                               \
            *(float4*)(outr + h) = hn;                                          \
            ACC.x = fmaf(hn.x, Wr[ch][0].x, ACC.x);                             \
            ACC.y = fmaf(hn.x, Wr[ch][0].y, ACC.y);                             \
            ACC.z = fmaf(hn.x, Wr[ch][0].z, ACC.z);                             \
            ACC.w = fmaf(hn.x, Wr[ch][0].w, ACC.w);                             \
            ACC.x = fmaf(hn.y, Wr[ch][1].x, ACC.x);                             \
            ACC.y = fmaf(hn.y, Wr[ch][1].y, ACC.y);                             \
            ACC.z = fmaf(hn.y, Wr[ch][1].z, ACC.z);                             \
            ACC.w = fmaf(hn.y, Wr[ch][1].w, ACC.w);                             \
            ACC.x = fmaf(hn.z, Wr[ch][2].x, ACC.x);                             \
            ACC.y = fmaf(hn.z, Wr[ch][2].y, ACC.y);                             \
            ACC.z = fmaf(hn.z, Wr[ch][2].z, ACC.z);                             \
            ACC.w = fmaf(hn.z, Wr[ch][2].w, ACC.w);                             \
            ACC.x = fmaf(hn.w, Wr[ch][3].x, ACC.x);                             \
            ACC.y = fmaf(hn.w, Wr[ch][3].y, ACC.y);                             \
            ACC.z = fmaf(hn.w, Wr[ch][3].z, ACC.z);                             \
            ACC.w = fmaf(hn.w, Wr[ch][3].w, ACC.w);                             \
        }                                                                       \
    }

    ROW_BODY(accA, 0)
    ROW_BODY(accB, 1)
    ROW_BODY(accC, 2)
    ROW_BODY(accD, 3)
#undef ROW_BODY

    // batched wave reduce-all: 4 independent chains (one per row)
#pragma unroll
    for (int off = 1; off < 64; off <<= 1) {
        accA.x += __shfl_xor(accA.x, off); accA.y += __shfl_xor(accA.y, off);
        accA.z += __shfl_xor(accA.z, off); accA.w += __shfl_xor(accA.w, off);
        accB.x += __shfl_xor(accB.x, off); accB.y += __shfl_xor(accB.y, off);
        accB.z += __shfl_xor(accB.z, off); accB.w += __shfl_xor(accB.w, off);
        accC.x += __shfl_xor(accC.x, off); accC.y += __shfl_xor(accC.y, off);
        accC.z += __shfl_xor(accC.z, off); accC.w += __shfl_xor(accC.w, off);
        accD.x += __shfl_xor(accD.x, off); accD.y += __shfl_xor(accD.y, off);
        accD.z += __shfl_xor(accD.z, off); accD.w += __shfl_xor(accD.w, off);
    }

    // lane-parallel epilogue: lane<16 handles (row r = lane>>2, expert n = lane&3)
    if (lane < 16) {
        const int r   = lane >> 2;
        const int n   = lane & 3;
        const int row = row0 + r;

        const float4 av = (r == 0) ? accA : (r == 1) ? accB : (r == 2) ? accC : accD;

        const float s0 = av.x + bias[0];
        const float s1 = av.y + bias[1];
        const float s2 = av.z + bias[2];
        const float s3 = av.w + bias[3];

        // first-occurrence argmax (matches jnp.argmax)
        int amax = 0; float best = s0;
        if (s1 > best) { best = s1; amax = 1; }
        if (s2 > best) { best = s2; amax = 2; }
        if (s3 > best) { best = s3; amax = 3; }

        const float e0 = expf(s0 - best);
        const float e1 = expf(s1 - best);
        const float e2 = expf(s2 - best);
        const float e3 = expf(s3 - best);
        const float inv = 1.0f / (e0 + e1 + e2 + e3);

        const int m = mask[row];
        const float rv = (m && n == amax) ? 1.0f : 0.0f;
        out[OUT_R + (size_t)row * 4 + n] = rv;
        if (m) {
            const float en = (n == 0 ? e0 : n == 1 ? e1 : n == 2 ? e2 : e3);
            atomicAdd(&pcn[labels[row] * 4 + n], en * inv * inv_w);
        }
    }
}

// Pass 4: info-gain finalize over p_cn (1000 x 4) -> scalar
__global__ void __launch_bounds__(256) k_ig(const float* __restrict__ pcn,
                                            float* __restrict__ out) {
    __shared__ float red[256];
    __shared__ float pn_sh[4];
    const int t = threadIdx.x;

    float pn[4] = {0.f, 0.f, 0.f, 0.f};
    for (int c = t; c < C_SZ; c += 256) {
        pn[0] += pcn[c * 4 + 0];
        pn[1] += pcn[c * 4 + 1];
        pn[2] += pcn[c * 4 + 2];
        pn[3] += pcn[c * 4 + 3];
    }
#pragma unroll
    for (int n = 0; n < 4; ++n) {
        red[t] = pn[n];
        __syncthreads();
        for (int sft = 128; sft > 0; sft >>= 1) {
            if (t < sft) red[t] += red[t + sft];
            __syncthreads();
        }
        if (t == 0) pn_sh[n] = red[0];
        __syncthreads();
    }

    const float l0 = 2.0f * logf(pn_sh[0] + 1e-30f);
    const float l1 = 2.0f * logf(pn_sh[1] + 1e-30f);
    const float l2 = 2.0f * logf(pn_sh[2] + 1e-30f);
    const float l3 = 2.0f * logf(pn_sh[3] + 1e-30f);

    float kv = 0.f;
    for (int c = t; c < C_SZ; c += 256) {
        const float v0 = pcn[c * 4 + 0];
        const float v1 = pcn[c * 4 + 1];
        const float v2 = pcn[c * 4 + 2];
        const float v3 = pcn[c * 4 + 3];
        const float pc  = v0 + v1 + v2 + v3;
        const float lpc = logf(pc + 1e-30f);
        kv += v0 * (logf(v0 + 1e-30f) - lpc - l0);
        kv += v1 * (logf(v1 + 1e-30f) - lpc - l1);
        kv += v2 * (logf(v2 + 1e-30f) - lpc - l2);
        kv += v3 * (logf(v3 + 1e-30f) - lpc - l3);
    }
    red[t] = kv;
    __syncthreads();
    for (int sft = 128; sft > 0; sft >>= 1) {
        if (t < sft) red[t] += red[t + sft];
        __syncthreads();
    }
    if (t == 0) out[OUT_IG] = -red[0];
}

extern "C" void kernel_launch(void* const* d_in, const int* in_sizes, int n_in,
                              void* d_out, int out_size, void* d_ws, size_t ws_size,
                              hipStream_t stream) {
    const int*   ig_mask = (const int*)d_in[0];
    const float* h_net   = (const float*)d_in[1];
    const int*   labels  = (const int*)d_in[2];
    const float* gamma   = (const float*)d_in[3];
    const float* beta    = (const float*)d_in[4];
    const float* W       = (const float*)d_in[5];
    const float* b       = (const float*)d_in[6];

    float* out = (float*)d_out;
    float* ws  = (float*)d_ws;

    k_colsum<<<ROW_BLOCKS, 256, 0, stream>>>(h_net, ig_mask, ws);
    k_colfinal<<<H_SZ / 8, 256, 0, stream>>>(gamma, beta, ws);
    k_fused<<<B_SZ / 16, 256, 0, stream>>>(h_net, ig_mask, labels, W, b, ws, out,
                                           ws + PCN_OFF);
    k_ig<<<1, 256, 0, stream>>>(ws + PCN_OFF, out);
}